// Round 5
// baseline (901.847 us; speedup 1.0000x reference)
//
#include <hip/hip_runtime.h>
#include <hip/hip_bf16.h>
#include <cstdint>
#include <cstddef>

typedef __hip_bfloat16 bf16;
typedef __attribute__((ext_vector_type(8))) short short8;
typedef __attribute__((ext_vector_type(4))) float f32x4;

// async global->LDS, 16B per lane. LDS dest = wave-uniform base + lane*16.
__device__ __forceinline__ void gload_lds16(const void* g, void* l) {
    __builtin_amdgcn_global_load_lds((const __attribute__((address_space(1))) void*)g,
                                     (__attribute__((address_space(3))) void*)l,
                                     16, 0, 0);
}

__device__ __forceinline__ void vm_wait6() { asm volatile("s_waitcnt vmcnt(6)" ::: "memory"); }
__device__ __forceinline__ void vm_wait0() { asm volatile("s_waitcnt vmcnt(0)" ::: "memory"); }
#define SBAR  asm volatile("s_barrier" ::: "memory")
#define LGKM0 asm volatile("s_waitcnt lgkmcnt(0)" ::: "memory")

__device__ __forceinline__ unsigned short f2bf_bits(float f) {
    bf16 h = __float2bfloat16(f);
    return *reinterpret_cast<unsigned short*>(&h);
}

// ------------- fp32 -> bf16 transpose: out[c][r] = bf16(in[r][c]) ------------
__global__ __launch_bounds__(256)
void transpose_cvt(const float* __restrict__ in, bf16* __restrict__ out, int R, int C)
{
    __shared__ float tile[32][33];
    const int tx = threadIdx.x & 31;
    const int ty = threadIdx.x >> 5;      // 0..7
    const int c0 = blockIdx.x * 32;
    const int r0 = blockIdx.y * 32;
    #pragma unroll
    for (int j = 0; j < 32; j += 8)
        tile[ty + j][tx] = in[(size_t)(r0 + ty + j) * C + c0 + tx];
    __syncthreads();
    #pragma unroll
    for (int j = 0; j < 32; j += 8)
        out[(size_t)(c0 + ty + j) * R + r0 + tx] = __float2bfloat16(tile[tx][ty + j]);
}

// ------------- fused per-tag table: ptab = (te@Wv+bv)@Wo+bo ------------------
// one block per tag row; t1 row lives in LDS (no global round-trip, 1 launch)
__global__ __launch_bounds__(256)
void tag_table(const float* __restrict__ te, const float* __restrict__ Wv,
               const float* __restrict__ bv, const float* __restrict__ Wo,
               const float* __restrict__ bo, float* __restrict__ ptab)
{
    __shared__ float t1[768];
    const int i = blockIdx.x;          // 0..63
    const int t = threadIdx.x;         // 0..255
    const float* a = te + (size_t)i * 768;
    #pragma unroll
    for (int jj = 0; jj < 3; ++jj) {
        const int j = t + jj * 256;
        float acc = bv[j];
        for (int k = 0; k < 768; ++k)
            acc += a[k] * Wv[(size_t)k * 768 + j];
        t1[j] = acc;
    }
    __syncthreads();
    #pragma unroll
    for (int jj = 0; jj < 3; ++jj) {
        const int j = t + jj * 256;
        float acc = bo[j];
        for (int k = 0; k < 768; ++k)
            acc += t1[k] * Wo[(size_t)k * 768 + j];
        ptab[(size_t)i * 768 + j] = acc;
    }
}

// ------------- x = we + ptab[tag]*mask; xn = bf16(LN1(x)) --------------------
// 192 threads (3 waves), one row, float4 loads, packed 8B bf16 stores (G13).
__global__ __launch_bounds__(192)
void addtag_ln(const float* __restrict__ we, const int* __restrict__ tags,
               const int* __restrict__ mask, const float* __restrict__ ptab,
               const float* __restrict__ g, const float* __restrict__ b,
               bf16* __restrict__ out)
{
    const int row = blockIdx.x;
    const int t = threadIdx.x;           // 0..191
    const int lane = t & 63, wid = t >> 6;
    const float msk = (float)mask[row];
    const float4 wv = ((const float4*)(we + (size_t)row * 768))[t];
    const float4 pv = ((const float4*)(ptab + (size_t)tags[row] * 768))[t];
    float4 x;
    x.x = wv.x + msk * pv.x;  x.y = wv.y + msk * pv.y;
    x.z = wv.z + msk * pv.z;  x.w = wv.w + msk * pv.w;
    float s  = x.x + x.y + x.z + x.w;
    float s2 = x.x * x.x + x.y * x.y + x.z * x.z + x.w * x.w;
    #pragma unroll
    for (int o = 32; o > 0; o >>= 1) { s += __shfl_down(s, o); s2 += __shfl_down(s2, o); }
    __shared__ float ls[3], ls2[3];
    if (lane == 0) { ls[wid] = s; ls2[wid] = s2; }
    __syncthreads();
    s  = ls[0] + ls[1] + ls[2];
    s2 = ls2[0] + ls2[1] + ls2[2];
    const float mean = s * (1.f / 768.f);
    float var = s2 * (1.f / 768.f) - mean * mean;
    var = var < 0.f ? 0.f : var;
    const float inv = 1.f / sqrtf(var + 1e-12f);
    const float4 gv = ((const float4*)g)[t];
    const float4 bv = ((const float4*)b)[t];
    uint2 o2;
    o2.x = (unsigned)f2bf_bits((x.x - mean) * inv * gv.x + bv.x)
         | ((unsigned)f2bf_bits((x.y - mean) * inv * gv.y + bv.y) << 16);
    o2.y = (unsigned)f2bf_bits((x.z - mean) * inv * gv.z + bv.z)
         | ((unsigned)f2bf_bits((x.w - mean) * inv * gv.w + bv.w) << 16);
    ((uint2*)(out + (size_t)row * 768))[t] = o2;
}

// ------------- in-place fp32 LN2 over d_out, float4 ------------------------
__global__ __launch_bounds__(192)
void ln_inplace(float* __restrict__ y, const float* __restrict__ g, const float* __restrict__ b)
{
    const int row = blockIdx.x;
    const int t = threadIdx.x;           // 0..191
    const int lane = t & 63, wid = t >> 6;
    float4* yr = (float4*)(y + (size_t)row * 768);
    const float4 x = yr[t];
    float s  = x.x + x.y + x.z + x.w;
    float s2 = x.x * x.x + x.y * x.y + x.z * x.z + x.w * x.w;
    #pragma unroll
    for (int o = 32; o > 0; o >>= 1) { s += __shfl_down(s, o); s2 += __shfl_down(s2, o); }
    __shared__ float ls[3], ls2[3];
    if (lane == 0) { ls[wid] = s; ls2[wid] = s2; }
    __syncthreads();
    s  = ls[0] + ls[1] + ls[2];
    s2 = ls2[0] + ls2[1] + ls2[2];
    const float mean = s * (1.f / 768.f);
    float var = s2 * (1.f / 768.f) - mean * mean;
    var = var < 0.f ? 0.f : var;
    const float inv = 1.f / sqrtf(var + 1e-12f);
    const float4 gv = ((const float4*)g)[t];
    const float4 bv = ((const float4*)b)[t];
    float4 o;
    o.x = (x.x - mean) * inv * gv.x + bv.x;
    o.y = (x.y - mean) * inv * gv.y + bv.y;
    o.z = (x.z - mean) * inv * gv.z + bv.z;
    o.w = (x.w - mean) * inv * gv.w + bv.w;
    yr[t] = o;
}

// ------------- 256x256 MFMA GEMM, BK=64, counted-vmcnt phase pipeline --------
// (byte-identical to the R1 PASSING 211-us schedule. Two structural variants
//  tried and retired: R2 quadrant (raced: A staged at P2 overwrote rows still
//  unread until P3 — staged halves are GLOBAL row-halves, wave reads straddle
//  both) and R4 lockstep quadrant (correct but 23% MfmaUtil vs 30% here —
//  barrier/SCHED0 lockstep beats compiler interleave negatively).)
template<int EPI, typename OutT>
__global__ __launch_bounds__(512, 2)
void gemm256(const bf16* __restrict__ A, const bf16* __restrict__ Bt,
             const float* __restrict__ bias, const bf16* __restrict__ resid,
             OutT* __restrict__ C, int N, int K, int nbx)
{
    extern __shared__ char smem[];
    char* const AsB = smem;            // 2 x 32768
    char* const BsB = smem + 65536;    // 2 x 32768

    const int t    = threadIdx.x;
    const int lane = t & 63;
    const int wid  = t >> 6;           // 0..7
    const int quad = lane >> 4;
    const int lr   = lane & 15;
    const int wmRow = (wid >> 2) * 128;   // 0 / 128
    const int wnRow = (wid & 3) * 64;     // 0/64/128/192

    // XCD-aware swizzle (requires nwg % 8 == 0; all our grids satisfy this)
    const int nwg = gridDim.x;
    const int swz = (blockIdx.x & 7) * (nwg >> 3) + (blockIdx.x >> 3);
    const int bx = swz % nbx;             // N-major: col-blocks sharing the
    const int by = swz / nbx;             // A row-panel are XCD-adjacent
    const int rowBase = by * 256;
    const int colBase = bx * 256;

    const char* const Ab = (const char*)(A + (size_t)rowBase * K);
    const char* const Bb = (const char*)(Bt + (size_t)colBase * K);
    const int strideB = K * 2;
    const int nkt = K >> 6;

    f32x4 acc[8][4] = {};

    // staging thread -> (local row, pre-swizzled source chunk). A half-tile is
    // 128 rows x 128B = 1024 chunks; 512 threads x 2 issues.
    const int i0 = t, i1 = t + 512;
    const int r0 = i0 >> 3, r1 = i1 >> 3;            // 0..127
    const int sc0 = ((i0 & 7) ^ (r0 & 7)) * 16;
    const int sc1 = ((i1 & 7) ^ (r1 & 7)) * 16;

    #define STAGE_A(buf_, kt_, h_) do {                                          \
        const int kb_ = (kt_) * 128;                                             \
        gload_lds16(Ab + (size_t)((h_)*128 + r0) * strideB + kb_ + sc0,          \
                    AsB + (buf_)*32768 + (h_)*16384 + i0*16);                    \
        gload_lds16(Ab + (size_t)((h_)*128 + r1) * strideB + kb_ + sc1,          \
                    AsB + (buf_)*32768 + (h_)*16384 + i1*16);                    \
    } while (0)
    #define STAGE_B(buf_, kt_, h_) do {                                          \
        const int kb_ = (kt_) * 128;                                             \
        gload_lds16(Bb + (size_t)((h_)*128 + r0) * strideB + kb_ + sc0,          \
                    BsB + (buf_)*32768 + (h_)*16384 + i0*16);                    \
        gload_lds16(Bb + (size_t)((h_)*128 + r1) * strideB + kb_ + sc1,          \
                    BsB + (buf_)*32768 + (h_)*16384 + i1*16);                    \
    } while (0)

    short8 af0[8], af1[8], bf0[4], bf1[4];
    #define RD_A(buf_, ks_, dst_) do {                                           \
        const int cch_ = (ks_)*4 + quad;                                         \
        _Pragma("unroll")                                                        \
        for (int mi = 0; mi < 8; ++mi) {                                         \
            const int R_ = wmRow + mi*16 + lr;                                   \
            dst_[mi] = *(const short8*)(AsB + (buf_)*32768 + R_*128 +            \
                                        ((cch_ ^ (R_ & 7)) * 16));               \
        }                                                                        \
    } while (0)
    #define RD_B(buf_, ks_, dst_) do {                                           \
        const int cch_ = (ks_)*4 + quad;                                         \
        _Pragma("unroll")                                                        \
        for (int ni = 0; ni < 4; ++ni) {                                         \
            const int R_ = wnRow + ni*16 + lr;                                   \
            dst_[ni] = *(const short8*)(BsB + (buf_)*32768 + R_*128 +            \
                                        ((cch_ ^ (R_ & 7)) * 16));               \
        }                                                                        \
    } while (0)
    #define MFMA8x2(AF_, BF_, n0_) do {                                          \
        __builtin_amdgcn_s_setprio(1);                                           \
        _Pragma("unroll")                                                        \
        for (int mi = 0; mi < 8; ++mi) {                                         \
            acc[mi][(n0_)]   = __builtin_amdgcn_mfma_f32_16x16x32_bf16(          \
                AF_[mi], BF_[(n0_)],   acc[mi][(n0_)],   0, 0, 0);               \
            acc[mi][(n0_)+1] = __builtin_amdgcn_mfma_f32_16x16x32_bf16(          \
                AF_[mi], BF_[(n0_)+1], acc[mi][(n0_)+1], 0, 0, 0);               \
        }                                                                        \
        __builtin_amdgcn_s_setprio(0);                                           \
    } while (0)

    // prologue: tile0 fully (4 half-tiles, oldest) + first 3 halves of tile1
    STAGE_A(0, 0, 0); STAGE_A(0, 0, 1); STAGE_B(0, 0, 0); STAGE_B(0, 0, 1);
    if (nkt > 1) { STAGE_A(1, 1, 0); STAGE_A(1, 1, 1); STAGE_B(1, 1, 0); }

    for (int kt = 0; kt < nkt; ++kt) {
        const int buf = kt & 1;
        if (kt == nkt - 1) vm_wait0(); else vm_wait6();  // tile kt fully landed
        SBAR;
        // P1
        RD_A(buf, 0, af0);
        RD_B(buf, 0, bf0);
        if (kt + 1 < nkt) STAGE_B(buf ^ 1, kt + 1, 1);   // last half of t+1
        MFMA8x2(af0, bf0, 0);
        SBAR;
        // P2
        RD_A(buf, 1, af1);
        RD_B(buf, 1, bf1);
        MFMA8x2(af0, bf0, 2);
        LGKM0;                                            // all reads of buf retired
        SBAR;                                             // -> buf dead block-wide
        // P3
        if (kt + 2 < nkt) { STAGE_A(buf, kt + 2, 0); STAGE_A(buf, kt + 2, 1); }
        MFMA8x2(af1, bf1, 0);
        SBAR;
        // P4
        if (kt + 2 < nkt) STAGE_B(buf, kt + 2, 0);
        MFMA8x2(af1, bf1, 2);
    }

    // D layout: row = quad*4 + reg, col = lane&15  [measured m89]
    #pragma unroll
    for (int ni = 0; ni < 4; ++ni) {
        const int gc = colBase + wnRow + ni * 16 + lr;
        const float bvv = bias[gc];
        #pragma unroll
        for (int mi = 0; mi < 8; ++mi) {
            const int gr0 = rowBase + wmRow + mi * 16 + quad * 4;
            #pragma unroll
            for (int r = 0; r < 4; ++r) {
                const size_t off = (size_t)(gr0 + r) * N + gc;
                float v = acc[mi][ni][r] + bvv;
                if (EPI == 0) {
                    v = v > 0.f ? v : 0.f;
                    C[off] = (OutT)__float2bfloat16(v);
                } else {
                    v += (float)resid[off];
                    C[off] = (OutT)v;
                }
            }
        }
    }
    #undef STAGE_A
    #undef STAGE_B
    #undef RD_A
    #undef RD_B
    #undef MFMA8x2
}

extern "C" void kernel_launch(void* const* d_in, const int* in_sizes, int n_in,
                              void* d_out, int out_size, void* d_ws, size_t ws_size,
                              hipStream_t stream)
{
    const float* we      = (const float*)d_in[0];
    const int*   tags    = (const int*)d_in[1];
    const int*   mask    = (const int*)d_in[2];
    const float* tag_emb = (const float*)d_in[3];
    const float* Wv      = (const float*)d_in[4];
    const float* bv      = (const float*)d_in[5];
    const float* Wo      = (const float*)d_in[6];
    const float* bo      = (const float*)d_in[7];
    const float* ln1g    = (const float*)d_in[8];
    const float* ln1b    = (const float*)d_in[9];
    const float* W1      = (const float*)d_in[10];
    const float* b1      = (const float*)d_in[11];
    const float* W2      = (const float*)d_in[12];
    const float* b2      = (const float*)d_in[13];
    const float* ln2g    = (const float*)d_in[14];
    const float* ln2b    = (const float*)d_in[15];
    float* out = (float*)d_out;

    // allow 128 KiB dynamic LDS for the 256^2 pipeline (once)
    static bool attr_set = false;
    if (!attr_set) {
        hipFuncSetAttribute(reinterpret_cast<const void*>(&gemm256<0, bf16>),
                            hipFuncAttributeMaxDynamicSharedMemorySize, 131072);
        hipFuncSetAttribute(reinterpret_cast<const void*>(&gemm256<1, float>),
                            hipFuncAttributeMaxDynamicSharedMemorySize, 131072);
        attr_set = true;
    }

    const int M = 8 * 4096;        // 32768 rows
    char* ws = (char*)d_ws;
    const size_t oPtab = 196608;               // 64*768*4      = 196608
    const size_t oW1t  = 393216;               // 3072*768*2    = 4718592
    const size_t oW2t  = 5111808;              // 768*3072*2    = 4718592
    const size_t oXn   = 9830400;              // 32768*768*2   = 50331648
    const size_t oHh   = 60162048;
    const size_t hhFull = (size_t)M * 3072 * 2;        // 201326592

    const int nchunk = (ws_size >= oHh + hhFull) ? 1 : 2;
    const int MC = M / nchunk;                 // multiple of 256 either way

    float* ptab = (float*)(ws + oPtab);
    bf16*  W1t  = (bf16*)(ws + oW1t);
    bf16*  W2t  = (bf16*)(ws + oW2t);
    bf16*  xn   = (bf16*)(ws + oXn);
    bf16*  hh   = (bf16*)(ws + oHh);           // MC*3072*2

    // weight transposes+convert: W1t[n][k] = bf16(W1[k][n]); W2t likewise
    transpose_cvt<<<dim3(3072 / 32, 768 / 32), 256, 0, stream>>>(W1, W1t, 768, 3072);
    transpose_cvt<<<dim3(768 / 32, 3072 / 32), 256, 0, stream>>>(W2, W2t, 3072, 768);

    // per-tag table (fp32), fused: ptab = (te@Wv+bv)@Wo+bo
    tag_table<<<64, 256, 0, stream>>>(tag_emb, Wv, bv, Wo, bo, ptab);

    // xn = bf16(LN1(we + ptab[tag]*mask))
    addtag_ln<<<M, 192, 0, stream>>>(we, tags, mask, ptab, ln1g, ln1b, xn);

    for (int c = 0; c < nchunk; ++c) {
        const bf16* xnC = xn + (size_t)c * MC * 768;
        const int nby = MC / 256;
        // hh = relu(xnC @ W1 + b1)   [bf16]   grid = 12*nby (%8 == 0)
        gemm256<0, bf16><<<(3072 / 256) * nby, 512, 131072, stream>>>(
            xnC, W1t, b1, nullptr, hh, 3072, 768, 3072 / 256);
        // y = hh @ W2 + b2 + xnC -> d_out chunk (fp32)   grid = 3*nby (%8 == 0)
        gemm256<1, float><<<(768 / 256) * nby, 512, 131072, stream>>>(
            hh, W2t, b2, xnC, out + (size_t)c * MC * 768, 768, 3072, 768 / 256);
    }

    // out = LN2(y), in place (fp32)
    ln_inplace<<<M, 192, 0, stream>>>(out, ln2g, ln2b);
}

// Round 6
// 711.784 us; speedup vs baseline: 1.2670x; 1.2670x over previous
//
#include <hip/hip_runtime.h>
#include <hip/hip_bf16.h>
#include <cstdint>
#include <cstddef>

typedef __hip_bfloat16 bf16;
typedef __attribute__((ext_vector_type(8))) short short8;
typedef __attribute__((ext_vector_type(4))) float f32x4;

// async global->LDS, 16B per lane. LDS dest = wave-uniform base + lane*16.
__device__ __forceinline__ void gload_lds16(const void* g, void* l) {
    __builtin_amdgcn_global_load_lds((const __attribute__((address_space(1))) void*)g,
                                     (__attribute__((address_space(3))) void*)l,
                                     16, 0, 0);
}

__device__ __forceinline__ void vm_wait6() { asm volatile("s_waitcnt vmcnt(6)" ::: "memory"); }
__device__ __forceinline__ void vm_wait0() { asm volatile("s_waitcnt vmcnt(0)" ::: "memory"); }
#define SBAR  asm volatile("s_barrier" ::: "memory")
#define LGKM0 asm volatile("s_waitcnt lgkmcnt(0)" ::: "memory")

__device__ __forceinline__ unsigned short f2bf_bits(float f) {
    bf16 h = __float2bfloat16(f);
    return *reinterpret_cast<unsigned short*>(&h);
}

// ------------- fp32 -> bf16 transpose: out[c][r] = bf16(in[r][c]) ------------
__global__ __launch_bounds__(256)
void transpose_cvt(const float* __restrict__ in, bf16* __restrict__ out, int R, int C)
{
    __shared__ float tile[32][33];
    const int tx = threadIdx.x & 31;
    const int ty = threadIdx.x >> 5;      // 0..7
    const int c0 = blockIdx.x * 32;
    const int r0 = blockIdx.y * 32;
    #pragma unroll
    for (int j = 0; j < 32; j += 8)
        tile[ty + j][tx] = in[(size_t)(r0 + ty + j) * C + c0 + tx];
    __syncthreads();
    #pragma unroll
    for (int j = 0; j < 32; j += 8)
        out[(size_t)(c0 + ty + j) * R + r0 + tx] = __float2bfloat16(tile[tx][ty + j]);
}

// ------------- per-tag table: ptab = (te@Wv+bv)@Wo+bo ------------------------
// R5's fused version was latency-bound (277us: 64 blocks x 256t, serial acc,
// dependent a[k] global loads). Fix: 768 threads/block (12 waves TLP), te/t1
// rows in LDS (no global scalar chain), 8 accumulators (8-way MLP).
__global__ __launch_bounds__(768)
void tag_table2(const float* __restrict__ te, const float* __restrict__ Wv,
                const float* __restrict__ bv, const float* __restrict__ Wo,
                const float* __restrict__ bo, float* __restrict__ ptab)
{
    __shared__ float as[768];
    __shared__ float t1s[768];
    const int i = blockIdx.x;          // tag 0..63
    const int j = threadIdx.x;         // 0..767
    as[j] = te[(size_t)i * 768 + j];
    __syncthreads();
    {
        float a0=0.f,a1=0.f,a2=0.f,a3=0.f,a4=0.f,a5=0.f,a6=0.f,a7=0.f;
        for (int k = 0; k < 768; k += 8) {
            a0 += as[k+0] * Wv[(size_t)(k+0) * 768 + j];
            a1 += as[k+1] * Wv[(size_t)(k+1) * 768 + j];
            a2 += as[k+2] * Wv[(size_t)(k+2) * 768 + j];
            a3 += as[k+3] * Wv[(size_t)(k+3) * 768 + j];
            a4 += as[k+4] * Wv[(size_t)(k+4) * 768 + j];
            a5 += as[k+5] * Wv[(size_t)(k+5) * 768 + j];
            a6 += as[k+6] * Wv[(size_t)(k+6) * 768 + j];
            a7 += as[k+7] * Wv[(size_t)(k+7) * 768 + j];
        }
        t1s[j] = (((a0+a1)+(a2+a3)) + ((a4+a5)+(a6+a7))) + bv[j];
    }
    __syncthreads();
    {
        float a0=0.f,a1=0.f,a2=0.f,a3=0.f,a4=0.f,a5=0.f,a6=0.f,a7=0.f;
        for (int k = 0; k < 768; k += 8) {
            a0 += t1s[k+0] * Wo[(size_t)(k+0) * 768 + j];
            a1 += t1s[k+1] * Wo[(size_t)(k+1) * 768 + j];
            a2 += t1s[k+2] * Wo[(size_t)(k+2) * 768 + j];
            a3 += t1s[k+3] * Wo[(size_t)(k+3) * 768 + j];
            a4 += t1s[k+4] * Wo[(size_t)(k+4) * 768 + j];
            a5 += t1s[k+5] * Wo[(size_t)(k+5) * 768 + j];
            a6 += t1s[k+6] * Wo[(size_t)(k+6) * 768 + j];
            a7 += t1s[k+7] * Wo[(size_t)(k+7) * 768 + j];
        }
        ptab[(size_t)i * 768 + j] = (((a0+a1)+(a2+a3)) + ((a4+a5)+(a6+a7))) + bo[j];
    }
}

// ------------- x = we + ptab[tag]*mask; xn = bf16(LN1(x)) --------------------
// 192 threads (3 waves), one row, float4 loads, packed 8B bf16 stores (G13).
__global__ __launch_bounds__(192)
void addtag_ln(const float* __restrict__ we, const int* __restrict__ tags,
               const int* __restrict__ mask, const float* __restrict__ ptab,
               const float* __restrict__ g, const float* __restrict__ b,
               bf16* __restrict__ out)
{
    const int row = blockIdx.x;
    const int t = threadIdx.x;           // 0..191
    const int lane = t & 63, wid = t >> 6;
    const float msk = (float)mask[row];
    const float4 wv = ((const float4*)(we + (size_t)row * 768))[t];
    const float4 pv = ((const float4*)(ptab + (size_t)tags[row] * 768))[t];
    float4 x;
    x.x = wv.x + msk * pv.x;  x.y = wv.y + msk * pv.y;
    x.z = wv.z + msk * pv.z;  x.w = wv.w + msk * pv.w;
    float s  = x.x + x.y + x.z + x.w;
    float s2 = x.x * x.x + x.y * x.y + x.z * x.z + x.w * x.w;
    #pragma unroll
    for (int o = 32; o > 0; o >>= 1) { s += __shfl_down(s, o); s2 += __shfl_down(s2, o); }
    __shared__ float ls[3], ls2[3];
    if (lane == 0) { ls[wid] = s; ls2[wid] = s2; }
    __syncthreads();
    s  = ls[0] + ls[1] + ls[2];
    s2 = ls2[0] + ls2[1] + ls2[2];
    const float mean = s * (1.f / 768.f);
    float var = s2 * (1.f / 768.f) - mean * mean;
    var = var < 0.f ? 0.f : var;
    const float inv = 1.f / sqrtf(var + 1e-12f);
    const float4 gv = ((const float4*)g)[t];
    const float4 bv = ((const float4*)b)[t];
    uint2 o2;
    o2.x = (unsigned)f2bf_bits((x.x - mean) * inv * gv.x + bv.x)
         | ((unsigned)f2bf_bits((x.y - mean) * inv * gv.y + bv.y) << 16);
    o2.y = (unsigned)f2bf_bits((x.z - mean) * inv * gv.z + bv.z)
         | ((unsigned)f2bf_bits((x.w - mean) * inv * gv.w + bv.w) << 16);
    ((uint2*)(out + (size_t)row * 768))[t] = o2;
}

// ------------- in-place fp32 LN2 over d_out, float4 ------------------------
__global__ __launch_bounds__(192)
void ln_inplace(float* __restrict__ y, const float* __restrict__ g, const float* __restrict__ b)
{
    const int row = blockIdx.x;
    const int t = threadIdx.x;           // 0..191
    const int lane = t & 63, wid = t >> 6;
    float4* yr = (float4*)(y + (size_t)row * 768);
    const float4 x = yr[t];
    float s  = x.x + x.y + x.z + x.w;
    float s2 = x.x * x.x + x.y * x.y + x.z * x.z + x.w * x.w;
    #pragma unroll
    for (int o = 32; o > 0; o >>= 1) { s += __shfl_down(s, o); s2 += __shfl_down(s2, o); }
    __shared__ float ls[3], ls2[3];
    if (lane == 0) { ls[wid] = s; ls2[wid] = s2; }
    __syncthreads();
    s  = ls[0] + ls[1] + ls[2];
    s2 = ls2[0] + ls2[1] + ls2[2];
    const float mean = s * (1.f / 768.f);
    float var = s2 * (1.f / 768.f) - mean * mean;
    var = var < 0.f ? 0.f : var;
    const float inv = 1.f / sqrtf(var + 1e-12f);
    const float4 gv = ((const float4*)g)[t];
    const float4 bv = ((const float4*)b)[t];
    float4 o;
    o.x = (x.x - mean) * inv * gv.x + bv.x;
    o.y = (x.y - mean) * inv * gv.y + bv.y;
    o.z = (x.z - mean) * inv * gv.z + bv.z;
    o.w = (x.w - mean) * inv * gv.w + bv.w;
    yr[t] = o;
}

// ------------- 256x256 MFMA GEMM, BK=64, counted-vmcnt phase pipeline --------
// (byte-identical to the R1 PASSING 211-us schedule. Two structural variants
//  tried and retired: R2 quadrant (raced: A staged at P2 overwrote rows still
//  unread until P3 — staged halves are GLOBAL row-halves, wave reads straddle
//  both) and R4 lockstep quadrant (correct but 23% MfmaUtil vs 30% here —
//  barrier/SCHED0 lockstep beats compiler interleave negatively).)
template<int EPI, typename OutT>
__global__ __launch_bounds__(512, 2)
void gemm256(const bf16* __restrict__ A, const bf16* __restrict__ Bt,
             const float* __restrict__ bias, const bf16* __restrict__ resid,
             OutT* __restrict__ C, int N, int K, int nbx)
{
    extern __shared__ char smem[];
    char* const AsB = smem;            // 2 x 32768
    char* const BsB = smem + 65536;    // 2 x 32768

    const int t    = threadIdx.x;
    const int lane = t & 63;
    const int wid  = t >> 6;           // 0..7
    const int quad = lane >> 4;
    const int lr   = lane & 15;
    const int wmRow = (wid >> 2) * 128;   // 0 / 128
    const int wnRow = (wid & 3) * 64;     // 0/64/128/192

    // XCD-aware swizzle (requires nwg % 8 == 0; all our grids satisfy this)
    const int nwg = gridDim.x;
    const int swz = (blockIdx.x & 7) * (nwg >> 3) + (blockIdx.x >> 3);
    const int bx = swz % nbx;             // N-major: col-blocks sharing the
    const int by = swz / nbx;             // A row-panel are XCD-adjacent
    const int rowBase = by * 256;
    const int colBase = bx * 256;

    const char* const Ab = (const char*)(A + (size_t)rowBase * K);
    const char* const Bb = (const char*)(Bt + (size_t)colBase * K);
    const int strideB = K * 2;
    const int nkt = K >> 6;

    f32x4 acc[8][4] = {};

    // staging thread -> (local row, pre-swizzled source chunk). A half-tile is
    // 128 rows x 128B = 1024 chunks; 512 threads x 2 issues.
    const int i0 = t, i1 = t + 512;
    const int r0 = i0 >> 3, r1 = i1 >> 3;            // 0..127
    const int sc0 = ((i0 & 7) ^ (r0 & 7)) * 16;
    const int sc1 = ((i1 & 7) ^ (r1 & 7)) * 16;

    #define STAGE_A(buf_, kt_, h_) do {                                          \
        const int kb_ = (kt_) * 128;                                             \
        gload_lds16(Ab + (size_t)((h_)*128 + r0) * strideB + kb_ + sc0,          \
                    AsB + (buf_)*32768 + (h_)*16384 + i0*16);                    \
        gload_lds16(Ab + (size_t)((h_)*128 + r1) * strideB + kb_ + sc1,          \
                    AsB + (buf_)*32768 + (h_)*16384 + i1*16);                    \
    } while (0)
    #define STAGE_B(buf_, kt_, h_) do {                                          \
        const int kb_ = (kt_) * 128;                                             \
        gload_lds16(Bb + (size_t)((h_)*128 + r0) * strideB + kb_ + sc0,          \
                    BsB + (buf_)*32768 + (h_)*16384 + i0*16);                    \
        gload_lds16(Bb + (size_t)((h_)*128 + r1) * strideB + kb_ + sc1,          \
                    BsB + (buf_)*32768 + (h_)*16384 + i1*16);                    \
    } while (0)

    short8 af0[8], af1[8], bf0[4], bf1[4];
    #define RD_A(buf_, ks_, dst_) do {                                           \
        const int cch_ = (ks_)*4 + quad;                                         \
        _Pragma("unroll")                                                        \
        for (int mi = 0; mi < 8; ++mi) {                                         \
            const int R_ = wmRow + mi*16 + lr;                                   \
            dst_[mi] = *(const short8*)(AsB + (buf_)*32768 + R_*128 +            \
                                        ((cch_ ^ (R_ & 7)) * 16));               \
        }                                                                        \
    } while (0)
    #define RD_B(buf_, ks_, dst_) do {                                           \
        const int cch_ = (ks_)*4 + quad;                                         \
        _Pragma("unroll")                                                        \
        for (int ni = 0; ni < 4; ++ni) {                                         \
            const int R_ = wnRow + ni*16 + lr;                                   \
            dst_[ni] = *(const short8*)(BsB + (buf_)*32768 + R_*128 +            \
                                        ((cch_ ^ (R_ & 7)) * 16));               \
        }                                                                        \
    } while (0)
    #define MFMA8x2(AF_, BF_, n0_) do {                                          \
        __builtin_amdgcn_s_setprio(1);                                           \
        _Pragma("unroll")                                                        \
        for (int mi = 0; mi < 8; ++mi) {                                         \
            acc[mi][(n0_)]   = __builtin_amdgcn_mfma_f32_16x16x32_bf16(          \
                AF_[mi], BF_[(n0_)],   acc[mi][(n0_)],   0, 0, 0);               \
            acc[mi][(n0_)+1] = __builtin_amdgcn_mfma_f32_16x16x32_bf16(          \
                AF_[mi], BF_[(n0_)+1], acc[mi][(n0_)+1], 0, 0, 0);               \
        }                                                                        \
        __builtin_amdgcn_s_setprio(0);                                           \
    } while (0)

    // prologue: tile0 fully (4 half-tiles, oldest) + first 3 halves of tile1
    STAGE_A(0, 0, 0); STAGE_A(0, 0, 1); STAGE_B(0, 0, 0); STAGE_B(0, 0, 1);
    if (nkt > 1) { STAGE_A(1, 1, 0); STAGE_A(1, 1, 1); STAGE_B(1, 1, 0); }

    for (int kt = 0; kt < nkt; ++kt) {
        const int buf = kt & 1;
        if (kt == nkt - 1) vm_wait0(); else vm_wait6();  // tile kt fully landed
        SBAR;
        // P1
        RD_A(buf, 0, af0);
        RD_B(buf, 0, bf0);
        if (kt + 1 < nkt) STAGE_B(buf ^ 1, kt + 1, 1);   // last half of t+1
        MFMA8x2(af0, bf0, 0);
        SBAR;
        // P2
        RD_A(buf, 1, af1);
        RD_B(buf, 1, bf1);
        MFMA8x2(af0, bf0, 2);
        LGKM0;                                            // all reads of buf retired
        SBAR;                                             // -> buf dead block-wide
        // P3
        if (kt + 2 < nkt) { STAGE_A(buf, kt + 2, 0); STAGE_A(buf, kt + 2, 1); }
        MFMA8x2(af1, bf1, 0);
        SBAR;
        // P4
        if (kt + 2 < nkt) STAGE_B(buf, kt + 2, 0);
        MFMA8x2(af1, bf1, 2);
    }

    // D layout: row = quad*4 + reg, col = lane&15  [measured m89]
    #pragma unroll
    for (int ni = 0; ni < 4; ++ni) {
        const int gc = colBase + wnRow + ni * 16 + lr;
        const float bvv = bias[gc];
        #pragma unroll
        for (int mi = 0; mi < 8; ++mi) {
            const int gr0 = rowBase + wmRow + mi * 16 + quad * 4;
            #pragma unroll
            for (int r = 0; r < 4; ++r) {
                const size_t off = (size_t)(gr0 + r) * N + gc;
                float v = acc[mi][ni][r] + bvv;
                if (EPI == 0) {
                    v = v > 0.f ? v : 0.f;
                    C[off] = (OutT)__float2bfloat16(v);
                } else {
                    v += (float)resid[off];
                    C[off] = (OutT)v;
                }
            }
        }
    }
    #undef STAGE_A
    #undef STAGE_B
    #undef RD_A
    #undef RD_B
    #undef MFMA8x2
}

extern "C" void kernel_launch(void* const* d_in, const int* in_sizes, int n_in,
                              void* d_out, int out_size, void* d_ws, size_t ws_size,
                              hipStream_t stream)
{
    const float* we      = (const float*)d_in[0];
    const int*   tags    = (const int*)d_in[1];
    const int*   mask    = (const int*)d_in[2];
    const float* tag_emb = (const float*)d_in[3];
    const float* Wv      = (const float*)d_in[4];
    const float* bv      = (const float*)d_in[5];
    const float* Wo      = (const float*)d_in[6];
    const float* bo      = (const float*)d_in[7];
    const float* ln1g    = (const float*)d_in[8];
    const float* ln1b    = (const float*)d_in[9];
    const float* W1      = (const float*)d_in[10];
    const float* b1      = (const float*)d_in[11];
    const float* W2      = (const float*)d_in[12];
    const float* b2      = (const float*)d_in[13];
    const float* ln2g    = (const float*)d_in[14];
    const float* ln2b    = (const float*)d_in[15];
    float* out = (float*)d_out;

    // allow 128 KiB dynamic LDS for the 256^2 pipeline (once)
    static bool attr_set = false;
    if (!attr_set) {
        hipFuncSetAttribute(reinterpret_cast<const void*>(&gemm256<0, bf16>),
                            hipFuncAttributeMaxDynamicSharedMemorySize, 131072);
        hipFuncSetAttribute(reinterpret_cast<const void*>(&gemm256<1, float>),
                            hipFuncAttributeMaxDynamicSharedMemorySize, 131072);
        attr_set = true;
    }

    const int M = 8 * 4096;        // 32768 rows
    char* ws = (char*)d_ws;
    const size_t oPtab = 196608;               // 64*768*4      = 196608
    const size_t oW1t  = 393216;               // 3072*768*2    = 4718592
    const size_t oW2t  = 5111808;              // 768*3072*2    = 4718592
    const size_t oXn   = 9830400;              // 32768*768*2   = 50331648
    const size_t oHh   = 60162048;
    const size_t hhFull = (size_t)M * 3072 * 2;        // 201326592

    const int nchunk = (ws_size >= oHh + hhFull) ? 1 : 2;
    const int MC = M / nchunk;                 // multiple of 256 either way

    float* ptab = (float*)(ws + oPtab);
    bf16*  W1t  = (bf16*)(ws + oW1t);
    bf16*  W2t  = (bf16*)(ws + oW2t);
    bf16*  xn   = (bf16*)(ws + oXn);
    bf16*  hh   = (bf16*)(ws + oHh);           // MC*3072*2

    // weight transposes+convert: W1t[n][k] = bf16(W1[k][n]); W2t likewise
    transpose_cvt<<<dim3(3072 / 32, 768 / 32), 256, 0, stream>>>(W1, W1t, 768, 3072);
    transpose_cvt<<<dim3(768 / 32, 3072 / 32), 256, 0, stream>>>(W2, W2t, 3072, 768);

    // per-tag table (fp32): ptab = (te@Wv+bv)@Wo+bo, latency-optimized
    tag_table2<<<64, 768, 0, stream>>>(tag_emb, Wv, bv, Wo, bo, ptab);

    // xn = bf16(LN1(we + ptab[tag]*mask))
    addtag_ln<<<M, 192, 0, stream>>>(we, tags, mask, ptab, ln1g, ln1b, xn);

    for (int c = 0; c < nchunk; ++c) {
        const bf16* xnC = xn + (size_t)c * MC * 768;
        const int nby = MC / 256;
        // hh = relu(xnC @ W1 + b1)   [bf16]   grid = 12*nby (%8 == 0)
        gemm256<0, bf16><<<(3072 / 256) * nby, 512, 131072, stream>>>(
            xnC, W1t, b1, nullptr, hh, 3072, 768, 3072 / 256);
        // y = hh @ W2 + b2 + xnC -> d_out chunk (fp32)   grid = 3*nby (%8 == 0)
        gemm256<1, float><<<(768 / 256) * nby, 512, 131072, stream>>>(
            hh, W2t, b2, xnC, out + (size_t)c * MC * 768, 768, 3072, 768 / 256);
    }

    // out = LN2(y), in place (fp32)
    ln_inplace<<<M, 192, 0, stream>>>(out, ln2g, ln2b);
}

// Round 7
// 693.585 us; speedup vs baseline: 1.3003x; 1.0262x over previous
//
#include <hip/hip_runtime.h>
#include <hip/hip_bf16.h>
#include <cstdint>
#include <cstddef>

typedef __hip_bfloat16 bf16;
typedef __attribute__((ext_vector_type(8))) short short8;
typedef __attribute__((ext_vector_type(4))) float f32x4;

// async global->LDS, 16B per lane. LDS dest = wave-uniform base + lane*16.
__device__ __forceinline__ void gload_lds16(const void* g, void* l) {
    __builtin_amdgcn_global_load_lds((const __attribute__((address_space(1))) void*)g,
                                     (__attribute__((address_space(3))) void*)l,
                                     16, 0, 0);
}

__device__ __forceinline__ void vm_wait6() { asm volatile("s_waitcnt vmcnt(6)" ::: "memory"); }
__device__ __forceinline__ void vm_wait0() { asm volatile("s_waitcnt vmcnt(0)" ::: "memory"); }
#define SBAR  asm volatile("s_barrier" ::: "memory")
#define LGKM0 asm volatile("s_waitcnt lgkmcnt(0)" ::: "memory")

__device__ __forceinline__ unsigned short f2bf_bits(float f) {
    bf16 h = __float2bfloat16(f);
    return *reinterpret_cast<unsigned short*>(&h);
}

// ------------- fp32 -> bf16 transpose: out[c][r] = bf16(in[r][c]) ------------
__global__ __launch_bounds__(256)
void transpose_cvt(const float* __restrict__ in, bf16* __restrict__ out, int R, int C)
{
    __shared__ float tile[32][33];
    const int tx = threadIdx.x & 31;
    const int ty = threadIdx.x >> 5;      // 0..7
    const int c0 = blockIdx.x * 32;
    const int r0 = blockIdx.y * 32;
    #pragma unroll
    for (int j = 0; j < 32; j += 8)
        tile[ty + j][tx] = in[(size_t)(r0 + ty + j) * C + c0 + tx];
    __syncthreads();
    #pragma unroll
    for (int j = 0; j < 32; j += 8)
        out[(size_t)(c0 + ty + j) * R + r0 + tx] = __float2bfloat16(tile[tx][ty + j]);
}

// ------------- per-tag table: ptab = (te@Wv+bv)@Wo+bo ------------------------
// 768 threads/block (12 waves TLP), te/t1 rows in LDS, 8 accumulators (MLP).
__global__ __launch_bounds__(768)
void tag_table2(const float* __restrict__ te, const float* __restrict__ Wv,
                const float* __restrict__ bv, const float* __restrict__ Wo,
                const float* __restrict__ bo, float* __restrict__ ptab)
{
    __shared__ float as[768];
    __shared__ float t1s[768];
    const int i = blockIdx.x;          // tag 0..63
    const int j = threadIdx.x;         // 0..767
    as[j] = te[(size_t)i * 768 + j];
    __syncthreads();
    {
        float a0=0.f,a1=0.f,a2=0.f,a3=0.f,a4=0.f,a5=0.f,a6=0.f,a7=0.f;
        for (int k = 0; k < 768; k += 8) {
            a0 += as[k+0] * Wv[(size_t)(k+0) * 768 + j];
            a1 += as[k+1] * Wv[(size_t)(k+1) * 768 + j];
            a2 += as[k+2] * Wv[(size_t)(k+2) * 768 + j];
            a3 += as[k+3] * Wv[(size_t)(k+3) * 768 + j];
            a4 += as[k+4] * Wv[(size_t)(k+4) * 768 + j];
            a5 += as[k+5] * Wv[(size_t)(k+5) * 768 + j];
            a6 += as[k+6] * Wv[(size_t)(k+6) * 768 + j];
            a7 += as[k+7] * Wv[(size_t)(k+7) * 768 + j];
        }
        t1s[j] = (((a0+a1)+(a2+a3)) + ((a4+a5)+(a6+a7))) + bv[j];
    }
    __syncthreads();
    {
        float a0=0.f,a1=0.f,a2=0.f,a3=0.f,a4=0.f,a5=0.f,a6=0.f,a7=0.f;
        for (int k = 0; k < 768; k += 8) {
            a0 += t1s[k+0] * Wo[(size_t)(k+0) * 768 + j];
            a1 += t1s[k+1] * Wo[(size_t)(k+1) * 768 + j];
            a2 += t1s[k+2] * Wo[(size_t)(k+2) * 768 + j];
            a3 += t1s[k+3] * Wo[(size_t)(k+3) * 768 + j];
            a4 += t1s[k+4] * Wo[(size_t)(k+4) * 768 + j];
            a5 += t1s[k+5] * Wo[(size_t)(k+5) * 768 + j];
            a6 += t1s[k+6] * Wo[(size_t)(k+6) * 768 + j];
            a7 += t1s[k+7] * Wo[(size_t)(k+7) * 768 + j];
        }
        ptab[(size_t)i * 768 + j] = (((a0+a1)+(a2+a3)) + ((a4+a5)+(a6+a7))) + bo[j];
    }
}

// ------------- x = we + ptab[tag]*mask; xn = bf16(LN1(x)) --------------------
// wave-per-row, grid-stride (G11): 4 waves/block x 2048 blocks, 3 float4/lane,
// reduction wave-local via shfl (no LDS, no __syncthreads). Old one-row-per-
// 192t-block version ran at ~1.2 TB/s (launch/barrier-bound, ~295us residual).
__global__ __launch_bounds__(256)
void addtag_ln(const float* __restrict__ we, const int* __restrict__ tags,
               const int* __restrict__ mask, const float* __restrict__ ptab,
               const float* __restrict__ g, const float* __restrict__ b,
               bf16* __restrict__ out, int M)
{
    const int wv   = threadIdx.x >> 6;    // 0..3
    const int lane = threadIdx.x & 63;
    const int rstep = gridDim.x * 4;
    float4 gv[3], bv[3];
    #pragma unroll
    for (int p = 0; p < 3; ++p) {
        gv[p] = ((const float4*)g)[lane + p * 64];
        bv[p] = ((const float4*)b)[lane + p * 64];
    }
    for (int row = blockIdx.x * 4 + wv; row < M; row += rstep) {
        const int   tag = tags[row];
        const float msk = (float)mask[row];
        const float4* wr = (const float4*)(we + (size_t)row * 768);
        const float4* pr = (const float4*)(ptab + (size_t)tag * 768);
        float4 x[3];
        float s = 0.f, s2 = 0.f;
        #pragma unroll
        for (int p = 0; p < 3; ++p) {
            const float4 wvv = wr[lane + p * 64];
            const float4 pvv = pr[lane + p * 64];
            float4 v;
            v.x = wvv.x + msk * pvv.x;  v.y = wvv.y + msk * pvv.y;
            v.z = wvv.z + msk * pvv.z;  v.w = wvv.w + msk * pvv.w;
            x[p] = v;
            s  += v.x + v.y + v.z + v.w;
            s2 += v.x * v.x + v.y * v.y + v.z * v.z + v.w * v.w;
        }
        #pragma unroll
        for (int o = 32; o > 0; o >>= 1) { s += __shfl_down(s, o); s2 += __shfl_down(s2, o); }
        s = __shfl(s, 0); s2 = __shfl(s2, 0);
        const float mean = s * (1.f / 768.f);
        float var = s2 * (1.f / 768.f) - mean * mean;
        var = var < 0.f ? 0.f : var;
        const float inv = 1.f / sqrtf(var + 1e-12f);
        uint2* orow = (uint2*)(out + (size_t)row * 768);
        #pragma unroll
        for (int p = 0; p < 3; ++p) {
            uint2 o2;
            o2.x = (unsigned)f2bf_bits((x[p].x - mean) * inv * gv[p].x + bv[p].x)
                 | ((unsigned)f2bf_bits((x[p].y - mean) * inv * gv[p].y + bv[p].y) << 16);
            o2.y = (unsigned)f2bf_bits((x[p].z - mean) * inv * gv[p].z + bv[p].z)
                 | ((unsigned)f2bf_bits((x[p].w - mean) * inv * gv[p].w + bv[p].w) << 16);
            orow[lane + p * 64] = o2;
        }
    }
}

// ------------- in-place fp32 LN2 over d_out: wave-per-row, grid-stride -------
__global__ __launch_bounds__(256)
void ln_inplace(float* __restrict__ y, const float* __restrict__ g,
                const float* __restrict__ b, int M)
{
    const int wv   = threadIdx.x >> 6;    // 0..3
    const int lane = threadIdx.x & 63;
    const int rstep = gridDim.x * 4;
    float4 gv[3], bv[3];
    #pragma unroll
    for (int p = 0; p < 3; ++p) {
        gv[p] = ((const float4*)g)[lane + p * 64];
        bv[p] = ((const float4*)b)[lane + p * 64];
    }
    for (int row = blockIdx.x * 4 + wv; row < M; row += rstep) {
        float4* yr = (float4*)(y + (size_t)row * 768);
        float4 x[3];
        float s = 0.f, s2 = 0.f;
        #pragma unroll
        for (int p = 0; p < 3; ++p) {
            const float4 v = yr[lane + p * 64];
            x[p] = v;
            s  += v.x + v.y + v.z + v.w;
            s2 += v.x * v.x + v.y * v.y + v.z * v.z + v.w * v.w;
        }
        #pragma unroll
        for (int o = 32; o > 0; o >>= 1) { s += __shfl_down(s, o); s2 += __shfl_down(s2, o); }
        s = __shfl(s, 0); s2 = __shfl(s2, 0);
        const float mean = s * (1.f / 768.f);
        float var = s2 * (1.f / 768.f) - mean * mean;
        var = var < 0.f ? 0.f : var;
        const float inv = 1.f / sqrtf(var + 1e-12f);
        #pragma unroll
        for (int p = 0; p < 3; ++p) {
            float4 o;
            o.x = (x[p].x - mean) * inv * gv[p].x + bv[p].x;
            o.y = (x[p].y - mean) * inv * gv[p].y + bv[p].y;
            o.z = (x[p].z - mean) * inv * gv[p].z + bv[p].z;
            o.w = (x[p].w - mean) * inv * gv[p].w + bv[p].w;
            yr[lane + p * 64] = o;
        }
    }
}

// ------------- 256x256 MFMA GEMM, BK=64, counted-vmcnt phase pipeline --------
// (byte-identical to the R1 PASSING 211-us schedule. Two structural variants
//  tried and retired: R2 quadrant (raced: A staged at P2 overwrote rows still
//  unread until P3) and R4 lockstep quadrant (correct but 23% vs 30% MfmaUtil).)
template<int EPI, typename OutT>
__global__ __launch_bounds__(512, 2)
void gemm256(const bf16* __restrict__ A, const bf16* __restrict__ Bt,
             const float* __restrict__ bias, const bf16* __restrict__ resid,
             OutT* __restrict__ C, int N, int K, int nbx)
{
    extern __shared__ char smem[];
    char* const AsB = smem;            // 2 x 32768
    char* const BsB = smem + 65536;    // 2 x 32768

    const int t    = threadIdx.x;
    const int lane = t & 63;
    const int wid  = t >> 6;           // 0..7
    const int quad = lane >> 4;
    const int lr   = lane & 15;
    const int wmRow = (wid >> 2) * 128;   // 0 / 128
    const int wnRow = (wid & 3) * 64;     // 0/64/128/192

    // XCD-aware swizzle (requires nwg % 8 == 0; all our grids satisfy this)
    const int nwg = gridDim.x;
    const int swz = (blockIdx.x & 7) * (nwg >> 3) + (blockIdx.x >> 3);
    const int bx = swz % nbx;             // N-major: col-blocks sharing the
    const int by = swz / nbx;             // A row-panel are XCD-adjacent
    const int rowBase = by * 256;
    const int colBase = bx * 256;

    const char* const Ab = (const char*)(A + (size_t)rowBase * K);
    const char* const Bb = (const char*)(Bt + (size_t)colBase * K);
    const int strideB = K * 2;
    const int nkt = K >> 6;

    f32x4 acc[8][4] = {};

    // staging thread -> (local row, pre-swizzled source chunk). A half-tile is
    // 128 rows x 128B = 1024 chunks; 512 threads x 2 issues.
    const int i0 = t, i1 = t + 512;
    const int r0 = i0 >> 3, r1 = i1 >> 3;            // 0..127
    const int sc0 = ((i0 & 7) ^ (r0 & 7)) * 16;
    const int sc1 = ((i1 & 7) ^ (r1 & 7)) * 16;

    #define STAGE_A(buf_, kt_, h_) do {                                          \
        const int kb_ = (kt_) * 128;                                             \
        gload_lds16(Ab + (size_t)((h_)*128 + r0) * strideB + kb_ + sc0,          \
                    AsB + (buf_)*32768 + (h_)*16384 + i0*16);                    \
        gload_lds16(Ab + (size_t)((h_)*128 + r1) * strideB + kb_ + sc1,          \
                    AsB + (buf_)*32768 + (h_)*16384 + i1*16);                    \
    } while (0)
    #define STAGE_B(buf_, kt_, h_) do {                                          \
        const int kb_ = (kt_) * 128;                                             \
        gload_lds16(Bb + (size_t)((h_)*128 + r0) * strideB + kb_ + sc0,          \
                    BsB + (buf_)*32768 + (h_)*16384 + i0*16);                    \
        gload_lds16(Bb + (size_t)((h_)*128 + r1) * strideB + kb_ + sc1,          \
                    BsB + (buf_)*32768 + (h_)*16384 + i1*16);                    \
    } while (0)

    short8 af0[8], af1[8], bf0[4], bf1[4];
    #define RD_A(buf_, ks_, dst_) do {                                           \
        const int cch_ = (ks_)*4 + quad;                                         \
        _Pragma("unroll")                                                        \
        for (int mi = 0; mi < 8; ++mi) {                                         \
            const int R_ = wmRow + mi*16 + lr;                                   \
            dst_[mi] = *(const short8*)(AsB + (buf_)*32768 + R_*128 +            \
                                        ((cch_ ^ (R_ & 7)) * 16));               \
        }                                                                        \
    } while (0)
    #define RD_B(buf_, ks_, dst_) do {                                           \
        const int cch_ = (ks_)*4 + quad;                                         \
        _Pragma("unroll")                                                        \
        for (int ni = 0; ni < 4; ++ni) {                                         \
            const int R_ = wnRow + ni*16 + lr;                                   \
            dst_[ni] = *(const short8*)(BsB + (buf_)*32768 + R_*128 +            \
                                        ((cch_ ^ (R_ & 7)) * 16));               \
        }                                                                        \
    } while (0)
    #define MFMA8x2(AF_, BF_, n0_) do {                                          \
        __builtin_amdgcn_s_setprio(1);                                           \
        _Pragma("unroll")                                                        \
        for (int mi = 0; mi < 8; ++mi) {                                         \
            acc[mi][(n0_)]   = __builtin_amdgcn_mfma_f32_16x16x32_bf16(          \
                AF_[mi], BF_[(n0_)],   acc[mi][(n0_)],   0, 0, 0);               \
            acc[mi][(n0_)+1] = __builtin_amdgcn_mfma_f32_16x16x32_bf16(          \
                AF_[mi], BF_[(n0_)+1], acc[mi][(n0_)+1], 0, 0, 0);               \
        }                                                                        \
        __builtin_amdgcn_s_setprio(0);                                           \
    } while (0)

    // prologue: tile0 fully (4 half-tiles, oldest) + first 3 halves of tile1
    STAGE_A(0, 0, 0); STAGE_A(0, 0, 1); STAGE_B(0, 0, 0); STAGE_B(0, 0, 1);
    if (nkt > 1) { STAGE_A(1, 1, 0); STAGE_A(1, 1, 1); STAGE_B(1, 1, 0); }

    for (int kt = 0; kt < nkt; ++kt) {
        const int buf = kt & 1;
        if (kt == nkt - 1) vm_wait0(); else vm_wait6();  // tile kt fully landed
        SBAR;
        // P1
        RD_A(buf, 0, af0);
        RD_B(buf, 0, bf0);
        if (kt + 1 < nkt) STAGE_B(buf ^ 1, kt + 1, 1);   // last half of t+1
        MFMA8x2(af0, bf0, 0);
        SBAR;
        // P2
        RD_A(buf, 1, af1);
        RD_B(buf, 1, bf1);
        MFMA8x2(af0, bf0, 2);
        LGKM0;                                            // all reads of buf retired
        SBAR;                                             // -> buf dead block-wide
        // P3
        if (kt + 2 < nkt) { STAGE_A(buf, kt + 2, 0); STAGE_A(buf, kt + 2, 1); }
        MFMA8x2(af1, bf1, 0);
        SBAR;
        // P4
        if (kt + 2 < nkt) STAGE_B(buf, kt + 2, 0);
        MFMA8x2(af1, bf1, 2);
    }

    // D layout: row = quad*4 + reg, col = lane&15  [measured m89]
    #pragma unroll
    for (int ni = 0; ni < 4; ++ni) {
        const int gc = colBase + wnRow + ni * 16 + lr;
        const float bvv = bias[gc];
        #pragma unroll
        for (int mi = 0; mi < 8; ++mi) {
            const int gr0 = rowBase + wmRow + mi * 16 + quad * 4;
            #pragma unroll
            for (int r = 0; r < 4; ++r) {
                const size_t off = (size_t)(gr0 + r) * N + gc;
                float v = acc[mi][ni][r] + bvv;
                if (EPI == 0) {
                    v = v > 0.f ? v : 0.f;
                    C[off] = (OutT)__float2bfloat16(v);
                } else {
                    v += (float)resid[off];
                    C[off] = (OutT)v;
                }
            }
        }
    }
    #undef STAGE_A
    #undef STAGE_B
    #undef RD_A
    #undef RD_B
    #undef MFMA8x2
}

extern "C" void kernel_launch(void* const* d_in, const int* in_sizes, int n_in,
                              void* d_out, int out_size, void* d_ws, size_t ws_size,
                              hipStream_t stream)
{
    const float* we      = (const float*)d_in[0];
    const int*   tags    = (const int*)d_in[1];
    const int*   mask    = (const int*)d_in[2];
    const float* tag_emb = (const float*)d_in[3];
    const float* Wv      = (const float*)d_in[4];
    const float* bv      = (const float*)d_in[5];
    const float* Wo      = (const float*)d_in[6];
    const float* bo      = (const float*)d_in[7];
    const float* ln1g    = (const float*)d_in[8];
    const float* ln1b    = (const float*)d_in[9];
    const float* W1      = (const float*)d_in[10];
    const float* b1      = (const float*)d_in[11];
    const float* W2      = (const float*)d_in[12];
    const float* b2      = (const float*)d_in[13];
    const float* ln2g    = (const float*)d_in[14];
    const float* ln2b    = (const float*)d_in[15];
    float* out = (float*)d_out;

    // allow 128 KiB dynamic LDS for the 256^2 pipeline (once)
    static bool attr_set = false;
    if (!attr_set) {
        hipFuncSetAttribute(reinterpret_cast<const void*>(&gemm256<0, bf16>),
                            hipFuncAttributeMaxDynamicSharedMemorySize, 131072);
        hipFuncSetAttribute(reinterpret_cast<const void*>(&gemm256<1, float>),
                            hipFuncAttributeMaxDynamicSharedMemorySize, 131072);
        attr_set = true;
    }

    const int M = 8 * 4096;        // 32768 rows
    char* ws = (char*)d_ws;
    const size_t oPtab = 196608;               // 64*768*4      = 196608
    const size_t oW1t  = 393216;               // 3072*768*2    = 4718592
    const size_t oW2t  = 5111808;              // 768*3072*2    = 4718592
    const size_t oXn   = 9830400;              // 32768*768*2   = 50331648
    const size_t oHh   = 60162048;
    const size_t hhFull = (size_t)M * 3072 * 2;        // 201326592

    const int nchunk = (ws_size >= oHh + hhFull) ? 1 : 2;
    const int MC = M / nchunk;                 // multiple of 256 either way

    float* ptab = (float*)(ws + oPtab);
    bf16*  W1t  = (bf16*)(ws + oW1t);
    bf16*  W2t  = (bf16*)(ws + oW2t);
    bf16*  xn   = (bf16*)(ws + oXn);
    bf16*  hh   = (bf16*)(ws + oHh);           // MC*3072*2

    // weight transposes+convert: W1t[n][k] = bf16(W1[k][n]); W2t likewise
    transpose_cvt<<<dim3(3072 / 32, 768 / 32), 256, 0, stream>>>(W1, W1t, 768, 3072);
    transpose_cvt<<<dim3(768 / 32, 3072 / 32), 256, 0, stream>>>(W2, W2t, 3072, 768);

    // per-tag table (fp32): ptab = (te@Wv+bv)@Wo+bo, latency-optimized
    tag_table2<<<64, 768, 0, stream>>>(tag_emb, Wv, bv, Wo, bo, ptab);

    // xn = bf16(LN1(we + ptab[tag]*mask))  — wave-per-row, grid-stride
    addtag_ln<<<2048, 256, 0, stream>>>(we, tags, mask, ptab, ln1g, ln1b, xn, M);

    for (int c = 0; c < nchunk; ++c) {
        const bf16* xnC = xn + (size_t)c * MC * 768;
        const int nby = MC / 256;
        // hh = relu(xnC @ W1 + b1)   [bf16]   grid = 12*nby (%8 == 0)
        gemm256<0, bf16><<<(3072 / 256) * nby, 512, 131072, stream>>>(
            xnC, W1t, b1, nullptr, hh, 3072, 768, 3072 / 256);
        // y = hh @ W2 + b2 + xnC -> d_out chunk (fp32)   grid = 3*nby (%8 == 0)
        gemm256<1, float><<<(768 / 256) * nby, 512, 131072, stream>>>(
            hh, W2t, b2, xnC, out + (size_t)c * MC * 768, 768, 3072, 768 / 256);
    }

    // out = LN2(y), in place (fp32) — wave-per-row, grid-stride
    ln_inplace<<<2048, 256, 0, stream>>>(out, ln2g, ln2b, M);
}

// Round 8
// 691.676 us; speedup vs baseline: 1.3039x; 1.0028x over previous
//
#include <hip/hip_runtime.h>
#include <hip/hip_bf16.h>
#include <cstdint>
#include <cstddef>

typedef __hip_bfloat16 bf16;
typedef __attribute__((ext_vector_type(8))) short short8;
typedef __attribute__((ext_vector_type(4))) float f32x4;

// async global->LDS, 16B per lane. LDS dest = wave-uniform base + lane*16.
__device__ __forceinline__ void gload_lds16(const void* g, void* l) {
    __builtin_amdgcn_global_load_lds((const __attribute__((address_space(1))) void*)g,
                                     (__attribute__((address_space(3))) void*)l,
                                     16, 0, 0);
}

__device__ __forceinline__ void vm_wait6() { asm volatile("s_waitcnt vmcnt(6)" ::: "memory"); }
__device__ __forceinline__ void vm_wait0() { asm volatile("s_waitcnt vmcnt(0)" ::: "memory"); }
#define SBAR  asm volatile("s_barrier" ::: "memory")
#define LGKM0 asm volatile("s_waitcnt lgkmcnt(0)" ::: "memory")

__device__ __forceinline__ unsigned short f2bf_bits(float f) {
    bf16 h = __float2bfloat16(f);
    return *reinterpret_cast<unsigned short*>(&h);
}

// ------------- fp32 -> bf16 transpose: out[c][r] = bf16(in[r][c]) ------------
__global__ __launch_bounds__(256)
void transpose_cvt(const float* __restrict__ in, bf16* __restrict__ out, int R, int C)
{
    __shared__ float tile[32][33];
    const int tx = threadIdx.x & 31;
    const int ty = threadIdx.x >> 5;      // 0..7
    const int c0 = blockIdx.x * 32;
    const int r0 = blockIdx.y * 32;
    #pragma unroll
    for (int j = 0; j < 32; j += 8)
        tile[ty + j][tx] = in[(size_t)(r0 + ty + j) * C + c0 + tx];
    __syncthreads();
    #pragma unroll
    for (int j = 0; j < 32; j += 8)
        out[(size_t)(c0 + ty + j) * R + r0 + tx] = __float2bfloat16(tile[tx][ty + j]);
}

// ------------- per-tag GEMV: out[i][j] = sum_k a[i][k]*W[k][j] + bias[j] -----
// Launched twice (te@Wv+bv -> t1; t1@Wo+bo -> ptab). 192 blocks (64 tags x 3
// j-chunks) x 256t: input row in LDS, 8 accumulators (8-deep MLP). Replaces
// tag_table2 (64 blocks: only 1/4 of CUs pulling from L2, ~87us).
__global__ __launch_bounds__(256)
void tag_gemv(const float* __restrict__ arows, const float* __restrict__ W,
              const float* __restrict__ bias, float* __restrict__ out)
{
    __shared__ float as[768];
    const int i = blockIdx.y;                     // tag 0..63
    const int j = blockIdx.x * 256 + threadIdx.x; // 0..767
    const float* a = arows + (size_t)i * 768;
    as[threadIdx.x]       = a[threadIdx.x];
    as[threadIdx.x + 256] = a[threadIdx.x + 256];
    as[threadIdx.x + 512] = a[threadIdx.x + 512];
    __syncthreads();
    float a0=0.f,a1=0.f,a2=0.f,a3=0.f,a4=0.f,a5=0.f,a6=0.f,a7=0.f;
    for (int k = 0; k < 768; k += 8) {
        a0 += as[k+0] * W[(size_t)(k+0) * 768 + j];
        a1 += as[k+1] * W[(size_t)(k+1) * 768 + j];
        a2 += as[k+2] * W[(size_t)(k+2) * 768 + j];
        a3 += as[k+3] * W[(size_t)(k+3) * 768 + j];
        a4 += as[k+4] * W[(size_t)(k+4) * 768 + j];
        a5 += as[k+5] * W[(size_t)(k+5) * 768 + j];
        a6 += as[k+6] * W[(size_t)(k+6) * 768 + j];
        a7 += as[k+7] * W[(size_t)(k+7) * 768 + j];
    }
    out[(size_t)i * 768 + j] = (((a0+a1)+(a2+a3)) + ((a4+a5)+(a6+a7))) + bias[j];
}

// ------------- x = we + ptab[tag]*mask; xn = bf16(LN1(x)) --------------------
// wave-per-row, grid-stride: 4 waves/block x 2048 blocks, 3 float4/lane,
// reduction wave-local via shfl (no LDS, no __syncthreads).
__global__ __launch_bounds__(256)
void addtag_ln(const float* __restrict__ we, const int* __restrict__ tags,
               const int* __restrict__ mask, const float* __restrict__ ptab,
               const float* __restrict__ g, const float* __restrict__ b,
               bf16* __restrict__ out, int M)
{
    const int wv   = threadIdx.x >> 6;    // 0..3
    const int lane = threadIdx.x & 63;
    const int rstep = gridDim.x * 4;
    float4 gv[3], bv[3];
    #pragma unroll
    for (int p = 0; p < 3; ++p) {
        gv[p] = ((const float4*)g)[lane + p * 64];
        bv[p] = ((const float4*)b)[lane + p * 64];
    }
    for (int row = blockIdx.x * 4 + wv; row < M; row += rstep) {
        const int   tag = tags[row];
        const float msk = (float)mask[row];
        const float4* wr = (const float4*)(we + (size_t)row * 768);
        const float4* pr = (const float4*)(ptab + (size_t)tag * 768);
        float4 x[3];
        float s = 0.f, s2 = 0.f;
        #pragma unroll
        for (int p = 0; p < 3; ++p) {
            const float4 wvv = wr[lane + p * 64];
            const float4 pvv = pr[lane + p * 64];
            float4 v;
            v.x = wvv.x + msk * pvv.x;  v.y = wvv.y + msk * pvv.y;
            v.z = wvv.z + msk * pvv.z;  v.w = wvv.w + msk * pvv.w;
            x[p] = v;
            s  += v.x + v.y + v.z + v.w;
            s2 += v.x * v.x + v.y * v.y + v.z * v.z + v.w * v.w;
        }
        #pragma unroll
        for (int o = 32; o > 0; o >>= 1) { s += __shfl_down(s, o); s2 += __shfl_down(s2, o); }
        s = __shfl(s, 0); s2 = __shfl(s2, 0);
        const float mean = s * (1.f / 768.f);
        float var = s2 * (1.f / 768.f) - mean * mean;
        var = var < 0.f ? 0.f : var;
        const float inv = 1.f / sqrtf(var + 1e-12f);
        uint2* orow = (uint2*)(out + (size_t)row * 768);
        #pragma unroll
        for (int p = 0; p < 3; ++p) {
            uint2 o2;
            o2.x = (unsigned)f2bf_bits((x[p].x - mean) * inv * gv[p].x + bv[p].x)
                 | ((unsigned)f2bf_bits((x[p].y - mean) * inv * gv[p].y + bv[p].y) << 16);
            o2.y = (unsigned)f2bf_bits((x[p].z - mean) * inv * gv[p].z + bv[p].z)
                 | ((unsigned)f2bf_bits((x[p].w - mean) * inv * gv[p].w + bv[p].w) << 16);
            orow[lane + p * 64] = o2;
        }
    }
}

// ------------- in-place fp32 LN2 over d_out: wave-per-row, grid-stride -------
__global__ __launch_bounds__(256)
void ln_inplace(float* __restrict__ y, const float* __restrict__ g,
                const float* __restrict__ b, int M)
{
    const int wv   = threadIdx.x >> 6;    // 0..3
    const int lane = threadIdx.x & 63;
    const int rstep = gridDim.x * 4;
    float4 gv[3], bv[3];
    #pragma unroll
    for (int p = 0; p < 3; ++p) {
        gv[p] = ((const float4*)g)[lane + p * 64];
        bv[p] = ((const float4*)b)[lane + p * 64];
    }
    for (int row = blockIdx.x * 4 + wv; row < M; row += rstep) {
        float4* yr = (float4*)(y + (size_t)row * 768);
        float4 x[3];
        float s = 0.f, s2 = 0.f;
        #pragma unroll
        for (int p = 0; p < 3; ++p) {
            const float4 v = yr[lane + p * 64];
            x[p] = v;
            s  += v.x + v.y + v.z + v.w;
            s2 += v.x * v.x + v.y * v.y + v.z * v.z + v.w * v.w;
        }
        #pragma unroll
        for (int o = 32; o > 0; o >>= 1) { s += __shfl_down(s, o); s2 += __shfl_down(s2, o); }
        s = __shfl(s, 0); s2 = __shfl(s2, 0);
        const float mean = s * (1.f / 768.f);
        float var = s2 * (1.f / 768.f) - mean * mean;
        var = var < 0.f ? 0.f : var;
        const float inv = 1.f / sqrtf(var + 1e-12f);
        #pragma unroll
        for (int p = 0; p < 3; ++p) {
            float4 o;
            o.x = (x[p].x - mean) * inv * gv[p].x + bv[p].x;
            o.y = (x[p].y - mean) * inv * gv[p].y + bv[p].y;
            o.z = (x[p].z - mean) * inv * gv[p].z + bv[p].z;
            o.w = (x[p].w - mean) * inv * gv[p].w + bv[p].w;
            yr[lane + p * 64] = o;
        }
    }
}

// ------------- 256x256 MFMA GEMM, BK=64, counted-vmcnt phase pipeline --------
// (byte-identical to the R1 PASSING 211-us schedule. Two structural variants
//  tried and retired: R2 quadrant (raced: A staged at P2 overwrote rows still
//  unread until P3) and R4 lockstep quadrant (correct but 23% vs 30% MfmaUtil).)
template<int EPI, typename OutT>
__global__ __launch_bounds__(512, 2)
void gemm256(const bf16* __restrict__ A, const bf16* __restrict__ Bt,
             const float* __restrict__ bias, const bf16* __restrict__ resid,
             OutT* __restrict__ C, int N, int K, int nbx)
{
    extern __shared__ char smem[];
    char* const AsB = smem;            // 2 x 32768
    char* const BsB = smem + 65536;    // 2 x 32768

    const int t    = threadIdx.x;
    const int lane = t & 63;
    const int wid  = t >> 6;           // 0..7
    const int quad = lane >> 4;
    const int lr   = lane & 15;
    const int wmRow = (wid >> 2) * 128;   // 0 / 128
    const int wnRow = (wid & 3) * 64;     // 0/64/128/192

    // XCD-aware swizzle (requires nwg % 8 == 0; all our grids satisfy this)
    const int nwg = gridDim.x;
    const int swz = (blockIdx.x & 7) * (nwg >> 3) + (blockIdx.x >> 3);
    const int bx = swz % nbx;             // N-major: col-blocks sharing the
    const int by = swz / nbx;             // A row-panel are XCD-adjacent
    const int rowBase = by * 256;
    const int colBase = bx * 256;

    const char* const Ab = (const char*)(A + (size_t)rowBase * K);
    const char* const Bb = (const char*)(Bt + (size_t)colBase * K);
    const int strideB = K * 2;
    const int nkt = K >> 6;

    f32x4 acc[8][4] = {};

    // staging thread -> (local row, pre-swizzled source chunk). A half-tile is
    // 128 rows x 128B = 1024 chunks; 512 threads x 2 issues.
    const int i0 = t, i1 = t + 512;
    const int r0 = i0 >> 3, r1 = i1 >> 3;            // 0..127
    const int sc0 = ((i0 & 7) ^ (r0 & 7)) * 16;
    const int sc1 = ((i1 & 7) ^ (r1 & 7)) * 16;

    #define STAGE_A(buf_, kt_, h_) do {                                          \
        const int kb_ = (kt_) * 128;                                             \
        gload_lds16(Ab + (size_t)((h_)*128 + r0) * strideB + kb_ + sc0,          \
                    AsB + (buf_)*32768 + (h_)*16384 + i0*16);                    \
        gload_lds16(Ab + (size_t)((h_)*128 + r1) * strideB + kb_ + sc1,          \
                    AsB + (buf_)*32768 + (h_)*16384 + i1*16);                    \
    } while (0)
    #define STAGE_B(buf_, kt_, h_) do {                                          \
        const int kb_ = (kt_) * 128;                                             \
        gload_lds16(Bb + (size_t)((h_)*128 + r0) * strideB + kb_ + sc0,          \
                    BsB + (buf_)*32768 + (h_)*16384 + i0*16);                    \
        gload_lds16(Bb + (size_t)((h_)*128 + r1) * strideB + kb_ + sc1,          \
                    BsB + (buf_)*32768 + (h_)*16384 + i1*16);                    \
    } while (0)

    short8 af0[8], af1[8], bf0[4], bf1[4];
    #define RD_A(buf_, ks_, dst_) do {                                           \
        const int cch_ = (ks_)*4 + quad;                                         \
        _Pragma("unroll")                                                        \
        for (int mi = 0; mi < 8; ++mi) {                                         \
            const int R_ = wmRow + mi*16 + lr;                                   \
            dst_[mi] = *(const short8*)(AsB + (buf_)*32768 + R_*128 +            \
                                        ((cch_ ^ (R_ & 7)) * 16));               \
        }                                                                        \
    } while (0)
    #define RD_B(buf_, ks_, dst_) do {                                           \
        const int cch_ = (ks_)*4 + quad;                                         \
        _Pragma("unroll")                                                        \
        for (int ni = 0; ni < 4; ++ni) {                                         \
            const int R_ = wnRow + ni*16 + lr;                                   \
            dst_[ni] = *(const short8*)(BsB + (buf_)*32768 + R_*128 +            \
                                        ((cch_ ^ (R_ & 7)) * 16));               \
        }                                                                        \
    } while (0)
    #define MFMA8x2(AF_, BF_, n0_) do {                                          \
        __builtin_amdgcn_s_setprio(1);                                           \
        _Pragma("unroll")                                                        \
        for (int mi = 0; mi < 8; ++mi) {                                         \
            acc[mi][(n0_)]   = __builtin_amdgcn_mfma_f32_16x16x32_bf16(          \
                AF_[mi], BF_[(n0_)],   acc[mi][(n0_)],   0, 0, 0);               \
            acc[mi][(n0_)+1] = __builtin_amdgcn_mfma_f32_16x16x32_bf16(          \
                AF_[mi], BF_[(n0_)+1], acc[mi][(n0_)+1], 0, 0, 0);               \
        }                                                                        \
        __builtin_amdgcn_s_setprio(0);                                           \
    } while (0)

    // prologue: tile0 fully (4 half-tiles, oldest) + first 3 halves of tile1
    STAGE_A(0, 0, 0); STAGE_A(0, 0, 1); STAGE_B(0, 0, 0); STAGE_B(0, 0, 1);
    if (nkt > 1) { STAGE_A(1, 1, 0); STAGE_A(1, 1, 1); STAGE_B(1, 1, 0); }

    for (int kt = 0; kt < nkt; ++kt) {
        const int buf = kt & 1;
        if (kt == nkt - 1) vm_wait0(); else vm_wait6();  // tile kt fully landed
        SBAR;
        // P1
        RD_A(buf, 0, af0);
        RD_B(buf, 0, bf0);
        if (kt + 1 < nkt) STAGE_B(buf ^ 1, kt + 1, 1);   // last half of t+1
        MFMA8x2(af0, bf0, 0);
        SBAR;
        // P2
        RD_A(buf, 1, af1);
        RD_B(buf, 1, bf1);
        MFMA8x2(af0, bf0, 2);
        LGKM0;                                            // all reads of buf retired
        SBAR;                                             // -> buf dead block-wide
        // P3
        if (kt + 2 < nkt) { STAGE_A(buf, kt + 2, 0); STAGE_A(buf, kt + 2, 1); }
        MFMA8x2(af1, bf1, 0);
        SBAR;
        // P4
        if (kt + 2 < nkt) STAGE_B(buf, kt + 2, 0);
        MFMA8x2(af1, bf1, 2);
    }

    // D layout: row = quad*4 + reg, col = lane&15  [measured m89]
    #pragma unroll
    for (int ni = 0; ni < 4; ++ni) {
        const int gc = colBase + wnRow + ni * 16 + lr;
        const float bvv = bias[gc];
        #pragma unroll
        for (int mi = 0; mi < 8; ++mi) {
            const int gr0 = rowBase + wmRow + mi * 16 + quad * 4;
            #pragma unroll
            for (int r = 0; r < 4; ++r) {
                const size_t off = (size_t)(gr0 + r) * N + gc;
                float v = acc[mi][ni][r] + bvv;
                if (EPI == 0) {
                    v = v > 0.f ? v : 0.f;
                    C[off] = (OutT)__float2bfloat16(v);
                } else {
                    v += (float)resid[off];
                    C[off] = (OutT)v;
                }
            }
        }
    }
    #undef STAGE_A
    #undef STAGE_B
    #undef RD_A
    #undef RD_B
    #undef MFMA8x2
}

extern "C" void kernel_launch(void* const* d_in, const int* in_sizes, int n_in,
                              void* d_out, int out_size, void* d_ws, size_t ws_size,
                              hipStream_t stream)
{
    const float* we      = (const float*)d_in[0];
    const int*   tags    = (const int*)d_in[1];
    const int*   mask    = (const int*)d_in[2];
    const float* tag_emb = (const float*)d_in[3];
    const float* Wv      = (const float*)d_in[4];
    const float* bv      = (const float*)d_in[5];
    const float* Wo      = (const float*)d_in[6];
    const float* bo      = (const float*)d_in[7];
    const float* ln1g    = (const float*)d_in[8];
    const float* ln1b    = (const float*)d_in[9];
    const float* W1      = (const float*)d_in[10];
    const float* b1      = (const float*)d_in[11];
    const float* W2      = (const float*)d_in[12];
    const float* b2      = (const float*)d_in[13];
    const float* ln2g    = (const float*)d_in[14];
    const float* ln2b    = (const float*)d_in[15];
    float* out = (float*)d_out;

    // allow 128 KiB dynamic LDS for the 256^2 pipeline (once)
    static bool attr_set = false;
    if (!attr_set) {
        hipFuncSetAttribute(reinterpret_cast<const void*>(&gemm256<0, bf16>),
                            hipFuncAttributeMaxDynamicSharedMemorySize, 131072);
        hipFuncSetAttribute(reinterpret_cast<const void*>(&gemm256<1, float>),
                            hipFuncAttributeMaxDynamicSharedMemorySize, 131072);
        attr_set = true;
    }

    const int M = 8 * 4096;        // 32768 rows
    char* ws = (char*)d_ws;
    const size_t oT1   = 0;                    // 64*768*4      = 196608
    const size_t oPtab = 196608;               // 64*768*4      = 196608
    const size_t oW1t  = 393216;               // 3072*768*2    = 4718592
    const size_t oW2t  = 5111808;              // 768*3072*2    = 4718592
    const size_t oXn   = 9830400;              // 32768*768*2   = 50331648
    const size_t oHh   = 60162048;
    const size_t hhFull = (size_t)M * 3072 * 2;        // 201326592

    const int nchunk = (ws_size >= oHh + hhFull) ? 1 : 2;
    const int MC = M / nchunk;                 // multiple of 256 either way

    float* t1   = (float*)(ws + oT1);
    float* ptab = (float*)(ws + oPtab);
    bf16*  W1t  = (bf16*)(ws + oW1t);
    bf16*  W2t  = (bf16*)(ws + oW2t);
    bf16*  xn   = (bf16*)(ws + oXn);
    bf16*  hh   = (bf16*)(ws + oHh);           // MC*3072*2

    // weight transposes+convert: W1t[n][k] = bf16(W1[k][n]); W2t likewise
    transpose_cvt<<<dim3(3072 / 32, 768 / 32), 256, 0, stream>>>(W1, W1t, 768, 3072);
    transpose_cvt<<<dim3(768 / 32, 3072 / 32), 256, 0, stream>>>(W2, W2t, 3072, 768);

    // per-tag table (fp32): t1 = te@Wv+bv; ptab = t1@Wo+bo  (192 blocks each)
    tag_gemv<<<dim3(3, 64), 256, 0, stream>>>(tag_emb, Wv, bv, t1);
    tag_gemv<<<dim3(3, 64), 256, 0, stream>>>(t1, Wo, bo, ptab);

    // xn = bf16(LN1(we + ptab[tag]*mask))  — wave-per-row, grid-stride
    addtag_ln<<<2048, 256, 0, stream>>>(we, tags, mask, ptab, ln1g, ln1b, xn, M);

    for (int c = 0; c < nchunk; ++c) {
        const bf16* xnC = xn + (size_t)c * MC * 768;
        const int nby = MC / 256;
        // hh = relu(xnC @ W1 + b1)   [bf16]   grid = 12*nby (%8 == 0)
        gemm256<0, bf16><<<(3072 / 256) * nby, 512, 131072, stream>>>(
            xnC, W1t, b1, nullptr, hh, 3072, 768, 3072 / 256);
        // y = hh @ W2 + b2 + xnC -> d_out chunk (fp32)   grid = 3*nby (%8 == 0)
        gemm256<1, float><<<(768 / 256) * nby, 512, 131072, stream>>>(
            hh, W2t, b2, xnC, out + (size_t)c * MC * 768, 768, 3072, 768 / 256);
    }

    // out = LN2(y), in place (fp32) — wave-per-row, grid-stride
    ln_inplace<<<2048, 256, 0, stream>>>(out, ln2g, ln2b, M);
}